// Round 3
// 1306.528 us; speedup vs baseline: 2.6740x; 2.6740x over previous
//
#include <hip/hip_runtime.h>
#include <stdint.h>

// MultiHeadAttention: B=4, S=2048, D_MODEL=512, H=8, dk=dv=64.
// ALL tensors fp32. fp32 math throughout.
// Round 4 (2nd resubmit after broker timeouts): rewrite attn_kernel. Old version
// was LDS-issue-bound (2 ds_read_b32 per fmac -> ~2.5ms of LDS serialization).
// New: 64 q-rows/block, two-phase:
//   P1: register-tiled (4x4/thread) QK^T -> raw scores to attn buf + online
//       row max/sumexp in registers (shfl_xor over the 16 lanes owning a row).
//   P2: re-read raw tile (L2-hot, same thread wrote it), exp-normalize,
//       overwrite attn with probs, register-tiled PV GEMM via LDS.
// 16 fmacs per 2 ds_read_b128 -> VALU-bound. No pr[] LDS, 34.8KB -> 4 blk/CU.

#define S_LEN 2048
#define DM 512
#define NH 8
#define DK 64

// -------- LayerNorm: one wave per row of 512, 4 rows per block --------
__global__ __launch_bounds__(256) void ln_kernel(const float* __restrict__ src,
    float* __restrict__ dst, const float* __restrict__ gw,
    const float* __restrict__ bw) {
  const int lane = threadIdx.x & 63;
  const int row  = blockIdx.x * 4 + (threadIdx.x >> 6);
  const size_t off = (size_t)row * DM + lane * 8;
  float4 a = *reinterpret_cast<const float4*>(src + off);
  float4 b = *reinterpret_cast<const float4*>(src + off + 4);
  float v[8] = {a.x, a.y, a.z, a.w, b.x, b.y, b.z, b.w};
  float s = 0.f, sq = 0.f;
#pragma unroll
  for (int i = 0; i < 8; i++) { s += v[i]; sq += v[i] * v[i]; }
#pragma unroll
  for (int m = 32; m > 0; m >>= 1) { s += __shfl_xor(s, m, 64); sq += __shfl_xor(sq, m, 64); }
  const float mu = s * (1.f / DM);
  const float var = sq * (1.f / DM) - mu * mu;
  const float rstd = rsqrtf(var + 1e-5f);
  float4 g0 = *reinterpret_cast<const float4*>(gw + lane * 8);
  float4 g1 = *reinterpret_cast<const float4*>(gw + lane * 8 + 4);
  float4 b0 = *reinterpret_cast<const float4*>(bw + lane * 8);
  float4 b1 = *reinterpret_cast<const float4*>(bw + lane * 8 + 4);
  float g[8] = {g0.x, g0.y, g0.z, g0.w, g1.x, g1.y, g1.z, g1.w};
  float bb[8] = {b0.x, b0.y, b0.z, b0.w, b1.x, b1.y, b1.z, b1.w};
  float o[8];
#pragma unroll
  for (int i = 0; i < 8; i++) o[i] = (v[i] - mu) * rstd * g[i] + bb[i];
  *reinterpret_cast<float4*>(dst + off)     = make_float4(o[0], o[1], o[2], o[3]);
  *reinterpret_cast<float4*>(dst + off + 4) = make_float4(o[4], o[5], o[6], o[7]);
}

// -------- GEMM: C[r,o] = sum_k A[r,k] * W[o,k]  (torch Linear, B^T form) --------
__global__ __launch_bounds__(256) void gemm_bt(const float* __restrict__ A,
    const float* __restrict__ W, float* __restrict__ C, int split) {
  __shared__ float As[16][68];
  __shared__ float Bs[16][68];
  const int t = threadIdx.x;
  const int tx = t & 15, ty = t >> 4;
  const int m0 = blockIdx.x * 64, n0 = blockIdx.y * 64;
  float acc[4][4] = {};
  const int lm = t >> 2;
  const int lk = (t & 3) * 4;
  for (int k0 = 0; k0 < DM; k0 += 16) {
    {
      float4 ra = *reinterpret_cast<const float4*>(A + (size_t)(m0 + lm) * DM + k0 + lk);
      As[lk + 0][lm] = ra.x; As[lk + 1][lm] = ra.y;
      As[lk + 2][lm] = ra.z; As[lk + 3][lm] = ra.w;
      float4 rb = *reinterpret_cast<const float4*>(W + (size_t)(n0 + lm) * DM + k0 + lk);
      Bs[lk + 0][lm] = rb.x; Bs[lk + 1][lm] = rb.y;
      Bs[lk + 2][lm] = rb.z; Bs[lk + 3][lm] = rb.w;
    }
    __syncthreads();
#pragma unroll
    for (int k = 0; k < 16; k++) {
      float4 av = *reinterpret_cast<const float4*>(&As[k][ty * 4]);
      float4 bv = *reinterpret_cast<const float4*>(&Bs[k][tx * 4]);
      float a_[4] = {av.x, av.y, av.z, av.w};
      float b_[4] = {bv.x, bv.y, bv.z, bv.w};
#pragma unroll
      for (int i = 0; i < 4; i++)
#pragma unroll
        for (int j = 0; j < 4; j++) acc[i][j] += a_[i] * b_[j];
    }
    __syncthreads();
  }
#pragma unroll
  for (int i = 0; i < 4; i++) {
    const int r = m0 + ty * 4 + i;
#pragma unroll
    for (int j = 0; j < 4; j++) {
      const int o = n0 + tx * 4 + j;
      if (split) {
        const int bb = r >> 11, ss = r & 2047, hh = o >> 6, dd = o & 63;
        C[(((size_t)(bb * NH + hh)) * S_LEN + ss) * DK + dd] = acc[i][j];
      } else {
        C[(size_t)r * DM + o] = acc[i][j];
      }
    }
  }
}

// -------- Fused attention, 64 q-rows per block, two-phase --------
// Block: 256 threads (tx = t&15 -> 4 cols, ty = t>>4 -> 4 rows). Grid (32,8,4).
// bufA: Q^T [d][i] in P1, P^T [j][i] in P2. bufB: K^T [d][j] in P1, V [j][d] in P2.
__global__ __launch_bounds__(256) void attn_kernel(const float* __restrict__ qh,
    const float* __restrict__ kh, const float* __restrict__ vh,
    float* __restrict__ attn, float* __restrict__ ctx) {
  __shared__ float bufA[64][68];
  __shared__ float bufB[64][68];
  const int t = threadIdx.x;
  const int tx = t & 15, ty = t >> 4;
  const int b = blockIdx.z, h = blockIdx.y, r0 = blockIdx.x * 64;
  const int bh = b * NH + h;
  const size_t base = (size_t)bh * S_LEN * DK;

  // ---- stage Q^T (once): bufA[d][i] ----
  {
    const int row = t & 63, dq = (t >> 6) * 16;
    const float* src = qh + base + (size_t)(r0 + row) * DK + dq;
#pragma unroll
    for (int c = 0; c < 16; c += 4) {
      float4 r4 = *reinterpret_cast<const float4*>(src + c);
      bufA[dq + c + 0][row] = r4.x;
      bufA[dq + c + 1][row] = r4.y;
      bufA[dq + c + 2][row] = r4.z;
      bufA[dq + c + 3][row] = r4.w;
    }
  }

  float m_run[4] = {-1e30f, -1e30f, -1e30f, -1e30f};
  float s_run[4] = {0.f, 0.f, 0.f, 0.f};

  // ---- phase 1: scores GEMM + online row stats + raw-score write ----
  for (int jt = 0; jt < 32; ++jt) {
    __syncthreads();  // prev GEMM reads of bufB done (also covers Q^T stage)
    {
      const int row = t & 63, dq = (t >> 6) * 16;
      const float* src = kh + base + (size_t)(jt * 64 + row) * DK + dq;
#pragma unroll
      for (int c = 0; c < 16; c += 4) {
        float4 r4 = *reinterpret_cast<const float4*>(src + c);
        bufB[dq + c + 0][row] = r4.x;
        bufB[dq + c + 1][row] = r4.y;
        bufB[dq + c + 2][row] = r4.z;
        bufB[dq + c + 3][row] = r4.w;
      }
    }
    __syncthreads();
    float acc[4][4] = {};
#pragma unroll 8
    for (int d = 0; d < 64; ++d) {
      float4 av = *reinterpret_cast<const float4*>(&bufA[d][ty * 4]);
      float4 bv = *reinterpret_cast<const float4*>(&bufB[d][tx * 4]);
      float a_[4] = {av.x, av.y, av.z, av.w};
      float b_[4] = {bv.x, bv.y, bv.z, bv.w};
#pragma unroll
      for (int i = 0; i < 4; i++)
#pragma unroll
        for (int j = 0; j < 4; j++) acc[i][j] += a_[i] * b_[j];
    }
    // scale, stats, raw write
#pragma unroll
    for (int ii = 0; ii < 4; ++ii) {
#pragma unroll
      for (int jj = 0; jj < 4; ++jj) acc[ii][jj] *= 0.125f;
      float tm = fmaxf(fmaxf(acc[ii][0], acc[ii][1]), fmaxf(acc[ii][2], acc[ii][3]));
#pragma unroll
      for (int m = 8; m > 0; m >>= 1) tm = fmaxf(tm, __shfl_xor(tm, m, 64));
      const float mn = fmaxf(m_run[ii], tm);
      float le = __expf(acc[ii][0] - mn) + __expf(acc[ii][1] - mn) +
                 __expf(acc[ii][2] - mn) + __expf(acc[ii][3] - mn);
#pragma unroll
      for (int m = 8; m > 0; m >>= 1) le += __shfl_xor(le, m, 64);
      s_run[ii] = s_run[ii] * __expf(m_run[ii] - mn) + le;
      m_run[ii] = mn;
      *reinterpret_cast<float4*>(attn +
          ((size_t)bh * S_LEN + r0 + ty * 4 + ii) * S_LEN + jt * 64 + tx * 4) =
          make_float4(acc[ii][0], acc[ii][1], acc[ii][2], acc[ii][3]);
    }
  }

  float inv_s[4], mfin[4];
#pragma unroll
  for (int ii = 0; ii < 4; ++ii) { inv_s[ii] = 1.f / s_run[ii]; mfin[ii] = m_run[ii]; }

  // ---- phase 2: normalize+write attn, PV GEMM ----
  float cacc[4][4] = {};
  for (int jt = 0; jt < 32; ++jt) {
    __syncthreads();  // prev PV reads done (first iter: last P1 GEMM reads done)
    float p[4][4];
    {
      const size_t rowbase =
          ((size_t)bh * S_LEN + r0 + ty * 4) * S_LEN + jt * 64 + tx * 4;
#pragma unroll
      for (int ii = 0; ii < 4; ++ii) {
        float4 r4 = *reinterpret_cast<const float4*>(attn + rowbase + (size_t)ii * S_LEN);
        p[ii][0] = __expf(r4.x - mfin[ii]) * inv_s[ii];
        p[ii][1] = __expf(r4.y - mfin[ii]) * inv_s[ii];
        p[ii][2] = __expf(r4.z - mfin[ii]) * inv_s[ii];
        p[ii][3] = __expf(r4.w - mfin[ii]) * inv_s[ii];
        *reinterpret_cast<float4*>(attn + rowbase + (size_t)ii * S_LEN) =
            make_float4(p[ii][0], p[ii][1], p[ii][2], p[ii][3]);
      }
    }
    // P^T into bufA: column write, one float4 per jj (contiguous in i)
#pragma unroll
    for (int jj = 0; jj < 4; ++jj) {
      *reinterpret_cast<float4*>(&bufA[tx * 4 + jj][ty * 4]) =
          make_float4(p[0][jj], p[1][jj], p[2][jj], p[3][jj]);
    }
    // stage V tile (natural layout [j][d])
    {
      const int row = t & 63, dq = (t >> 6) * 16;
      const float* src = vh + base + (size_t)(jt * 64 + row) * DK + dq;
#pragma unroll
      for (int c = 0; c < 16; c += 4) {
        *reinterpret_cast<float4*>(&bufB[row][dq + c]) =
            *reinterpret_cast<const float4*>(src + c);
      }
    }
    __syncthreads();
#pragma unroll 8
    for (int j = 0; j < 64; ++j) {
      float4 pa = *reinterpret_cast<const float4*>(&bufA[j][ty * 4]);
      float4 vv = *reinterpret_cast<const float4*>(&bufB[j][tx * 4]);
      float a_[4] = {pa.x, pa.y, pa.z, pa.w};
      float b_[4] = {vv.x, vv.y, vv.z, vv.w};
#pragma unroll
      for (int i = 0; i < 4; i++)
#pragma unroll
        for (int j2 = 0; j2 < 4; j2++) cacc[i][j2] += a_[i] * b_[j2];
    }
  }

  // ---- write ctx [B,S,DM] with head offset ----
#pragma unroll
  for (int ii = 0; ii < 4; ++ii) {
    *reinterpret_cast<float4*>(ctx +
        ((size_t)b * S_LEN + r0 + ty * 4 + ii) * DM + h * DK + tx * 4) =
        make_float4(cacc[ii][0], cacc[ii][1], cacc[ii][2], cacc[ii][3]);
  }
}

extern "C" void kernel_launch(void* const* d_in, const int* in_sizes, int n_in,
                              void* d_out, int out_size, void* d_ws, size_t ws_size,
                              hipStream_t stream) {
  const float* q   = (const float*)d_in[0];
  const float* k   = (const float*)d_in[1];
  const float* v   = (const float*)d_in[2];
  const float* Wq  = (const float*)d_in[3];
  const float* Wk  = (const float*)d_in[4];
  const float* Wv  = (const float*)d_in[5];
  const float* Wfc = (const float*)d_in[6];
  const float* g   = (const float*)d_in[7];
  const float* bb  = (const float*)d_in[8];

  float* out  = (float*)d_out;
  const size_t NE = (size_t)4 * S_LEN * DM;  // 4,194,304 elements
  float* attn = out + NE;                    // output 1 follows output 0

  // Workspace (fp32): 3 buffers x 16.8 MB = 50.3 MB.
  float* buf0 = (float*)d_ws;        // LN scratch, later ctx
  float* buf1 = buf0 + NE;           // qh, later LN(ctx)
  float* buf2 = buf0 + 2 * NE;       // kh
  float* vhb  = out;                 // vh staged in out0 region (dead until final GEMM)

  ln_kernel<<<2048, 256, 0, stream>>>(q, buf0, g, bb);
  gemm_bt<<<dim3(128, 8), 256, 0, stream>>>(buf0, Wq, buf1, 1);

  ln_kernel<<<2048, 256, 0, stream>>>(k, buf0, g, bb);
  gemm_bt<<<dim3(128, 8), 256, 0, stream>>>(buf0, Wk, buf2, 1);

  ln_kernel<<<2048, 256, 0, stream>>>(v, buf0, g, bb);
  gemm_bt<<<dim3(128, 8), 256, 0, stream>>>(buf0, Wv, vhb, 1);

  attn_kernel<<<dim3(32, 8, 4), 256, 0, stream>>>(buf1, buf2, vhb, attn, buf0);

  ln_kernel<<<2048, 256, 0, stream>>>(buf0, buf1, g, bb);
  gemm_bt<<<dim3(128, 8), 256, 0, stream>>>(buf1, Wfc, out, 0);
}